// Round 5
// baseline (187.041 us; speedup 1.0000x reference)
//
#include <hip/hip_runtime.h>
#include <math.h>

#define EMB_DIM 512
#define N_Q 8
#define GAMMA_F 12.0f

// ---------------------------------------------------------------------------
// RotatE scoring, barrier-free version.
//
// Block = 4 waves. Wave w owns queries {2w, 2w+1} over the FULL entity row.
// All 4 waves of a block stream the same rows (grid-stride by blockIdx), so
// 3/4 of the row loads hit L1/L2 (4 MiB per-XCD L2 absorbs wave drift) and
// HBM traffic stays ~120 MB. There is NO inter-wave communication: no LDS,
// no __syncthreads in the loop — each wave reduces its 2 query sums with 6
// shfl ops and lanes 0/1 store them. Per-lane query state is 32 floats
// (8 VGPRs x4), computed in-register at init via __sincosf (no lq LDS).
//
// Lane l covers dims {4l..4l+3} and {256+4l..256+4l+3}: row loads are
// 4 x global_load_dwordx4, each 1 KiB contiguous per wave. Depth-1 register
// prefetch keeps 4 KiB/wave in flight; 16 waves/CU -> plenty to saturate HBM.
// ---------------------------------------------------------------------------

__device__ __forceinline__ void rot4(const float4 reh, const float4 imh,
                                     const float4 ph, float scale,
                                     float4* qr, float4* qi)
{
    float s, c;
    __sincosf(ph.x * scale, &s, &c); qr->x = reh.x * c - imh.x * s; qi->x = reh.x * s + imh.x * c;
    __sincosf(ph.y * scale, &s, &c); qr->y = reh.y * c - imh.y * s; qi->y = reh.y * s + imh.y * c;
    __sincosf(ph.z * scale, &s, &c); qr->z = reh.z * c - imh.z * s; qi->z = reh.z * s + imh.z * c;
    __sincosf(ph.w * scale, &s, &c); qr->w = reh.w * c - imh.w * s; qi->w = reh.w * s + imh.w * c;
}

#define ACC4(qr4, qi4, er4, ei4, s) do {                                          \
    float dx_, dy_;                                                               \
    dx_ = (qr4).x - (er4).x; dy_ = (qi4).x - (ei4).x; s += __builtin_amdgcn_sqrtf(fmaf(dx_, dx_, dy_ * dy_)); \
    dx_ = (qr4).y - (er4).y; dy_ = (qi4).y - (ei4).y; s += __builtin_amdgcn_sqrtf(fmaf(dx_, dx_, dy_ * dy_)); \
    dx_ = (qr4).z - (er4).z; dy_ = (qi4).z - (ei4).z; s += __builtin_amdgcn_sqrtf(fmaf(dx_, dx_, dy_ * dy_)); \
    dx_ = (qr4).w - (er4).w; dy_ = (qi4).w - (ei4).w; s += __builtin_amdgcn_sqrtf(fmaf(dx_, dx_, dy_ * dy_)); \
} while (0)

__global__ __launch_bounds__(256, 4) void rotate_fused_kernel(
    const int* __restrict__ all_h,
    const int* __restrict__ all_r,
    const float* __restrict__ eemb,
    const float* __restrict__ remb,
    float* __restrict__ out,
    int N)
{
    const int tid  = threadIdx.x;
    const int lane = tid & 63;
    const int wid  = tid >> 6;
    const int b0   = wid << 1;                 // this wave's queries: b0, b0+1

    const float SCALE = (float)(M_PI * (double)EMB_DIM / 14.0);

    // ---- init: rotated query fragments, strictly in registers ----
    // dims lo = 4*lane..+3, hi = 256+4*lane..+3, for 2 queries: 32 floats.
    float4 qr_lo[2], qr_hi[2], qi_lo[2], qi_hi[2];
    #pragma unroll
    for (int qq = 0; qq < 2; ++qq) {
        int b = b0 + qq;
        int h = all_h[b];
        int r = all_r[b];
        const float* hrow = eemb + (size_t)h * (2 * EMB_DIM);
        const float* rrow = remb + (size_t)r * EMB_DIM;
        const int dlo = 4 * lane, dhi = 256 + 4 * lane;
        float4 reh, imh, ph;
        reh = *(const float4*)(hrow + dlo);
        imh = *(const float4*)(hrow + EMB_DIM + dlo);
        ph  = *(const float4*)(rrow + dlo);
        rot4(reh, imh, ph, SCALE, &qr_lo[qq], &qi_lo[qq]);
        reh = *(const float4*)(hrow + dhi);
        imh = *(const float4*)(hrow + EMB_DIM + dhi);
        ph  = *(const float4*)(rrow + dhi);
        rot4(reh, imh, ph, SCALE, &qr_hi[qq], &qi_hi[qq]);
    }

    // ---- stream entities, depth-1 register prefetch, no barriers ----
    const int stride = gridDim.x;
    int n = blockIdx.x;
    if (n >= N) return;

    const float* bp = eemb + 4 * lane;   // + row*1024: re_lo(0) re_hi(256) im_lo(512) im_hi(768)

    float4 c0, c1, c2, c3;
    {
        const float* p = bp + (size_t)n * (2 * EMB_DIM);
        c0 = *(const float4*)(p);
        c1 = *(const float4*)(p + 256);
        c2 = *(const float4*)(p + 512);
        c3 = *(const float4*)(p + 768);
    }

    while (true) {
        const int n2 = n + stride;
        float4 p0, p1, p2, p3;
        {
            const int nc = (n2 < N) ? n2 : 0;
            const float* p = bp + (size_t)nc * (2 * EMB_DIM);
            p0 = *(const float4*)(p);
            p1 = *(const float4*)(p + 256);
            p2 = *(const float4*)(p + 512);
            p3 = *(const float4*)(p + 768);
        }

        float s0 = 0.f, s1 = 0.f;
        ACC4(qr_lo[0], qi_lo[0], c0, c2, s0);
        ACC4(qr_hi[0], qi_hi[0], c1, c3, s0);
        ACC4(qr_lo[1], qi_lo[1], c0, c2, s1);
        ACC4(qr_hi[1], qi_hi[1], c1, c3, s1);

        // transposing butterfly: even lanes carry query b0, odd carry b0+1
        const bool po = lane & 1;
        float x = po ? s1 : s0;
        float z = po ? s0 : s1;
        x += __shfl_xor(z, 1);
        x += __shfl_xor(x, 2);
        x += __shfl_xor(x, 4);
        x += __shfl_xor(x, 8);
        x += __shfl_xor(x, 16);
        x += __shfl_xor(x, 32);
        if (lane < 2) out[(size_t)(b0 + lane) * N + n] = GAMMA_F - x;

        if (n2 >= N) break;
        n = n2;
        c0 = p0; c1 = p1; c2 = p2; c3 = p3;
    }
}

extern "C" void kernel_launch(void* const* d_in, const int* in_sizes, int n_in,
                              void* d_out, int out_size, void* d_ws, size_t ws_size,
                              hipStream_t stream) {
    const int*   all_h = (const int*)d_in[0];
    const int*   all_r = (const int*)d_in[1];
    const float* eemb  = (const float*)d_in[2];
    const float* remb  = (const float*)d_in[3];
    float* out = (float*)d_out;

    int N = in_sizes[2] / (2 * EMB_DIM);   // 30000

    // 1024 blocks = 4 blocks/CU co-resident (16 waves/CU), one entity per
    // block-iteration, all 4 waves on the same row (L2-shared).
    rotate_fused_kernel<<<1024, 256, 0, stream>>>(all_h, all_r, eemb, remb, out, N);
}